// Round 7
// baseline (2926.708 us; speedup 1.0000x reference)
//
#include <hip/hip_runtime.h>

typedef __bf16 bf16;
typedef __bf16 bf16x8 __attribute__((ext_vector_type(8)));
typedef float f32x4 __attribute__((ext_vector_type(4)));
typedef float f32x16 __attribute__((ext_vector_type(16)));

#define Tt 64
#define Bb 1024
#define Dd 128
#define Ee 256
#define Hh 512
#define H3 1536

__device__ __forceinline__ float sigmf(float x) { return 1.0f / (1.0f + __expf(-x)); }
__device__ __forceinline__ float tanhfast(float x) {
    float e = __expf(2.0f * x);
    return 1.0f - 2.0f / (e + 1.0f);
}

// agent-scope (device-coherent) ops; coherence point = memory-side L3.
#define LD_SC(dst, bp) \
    asm volatile("global_load_dwordx4 %0, %1, off sc1" : "=v"(dst) : "v"(bp))
#define ST_SCX4(bp, val) \
    asm volatile("global_store_dwordx4 %0, %1, off sc1" :: "v"(bp), "v"(val))

// ---------------- fused weight prep: f32 [K][N] -> bf16 [N][K] for all 6 weights ----------------
__global__ void k_prep(const float* __restrict__ We, const float* __restrict__ Wie, const float* __restrict__ Whe,
                       const float* __restrict__ Wid, const float* __restrict__ Whd, const float* __restrict__ Wo,
                       bf16* __restrict__ dWe, bf16* __restrict__ dWie, bf16* __restrict__ dWhe,
                       bf16* __restrict__ dWid, bf16* __restrict__ dWhd, bf16* __restrict__ dWo) {
    long i = (long)blockIdx.x * 256 + threadIdx.x;
    const float* s;
    bf16* d;
    int K, N;
    if (i < 32768) { s = We; d = dWe; K = Dd; N = Ee; }
    else if ((i -= 32768) < 393216) { s = Wie; d = dWie; K = Ee; N = H3; }
    else if ((i -= 393216) < 786432) { s = Whe; d = dWhe; K = Hh; N = H3; }
    else if ((i -= 786432) < 393216) { s = Wid; d = dWid; K = Ee; N = H3; }
    else if ((i -= 393216) < 786432) { s = Whd; d = dWhd; K = Hh; N = H3; }
    else if ((i -= 786432) < 65536) { s = Wo; d = dWo; K = Hh; N = Dd; }
    else return;
    int n = (int)(i / K), k = (int)(i - (long)n * K);
    d[i] = (bf16)s[(size_t)k * N + n];
}

// ---------------- embed: relu(x @ W_emb + b); past (z=0) and future (z=1) fused ----------------
__global__ __launch_bounds__(256) void k_embed(const float* __restrict__ xP, const float* __restrict__ xF,
                                               const bf16* __restrict__ WT, const float* __restrict__ bias,
                                               bf16* __restrict__ oP, bf16* __restrict__ oF) {
    const int lane = threadIdx.x & 63, wv = threadIdx.x >> 6;
    const float* x = blockIdx.z ? xF : xP;
    bf16* o = blockIdx.z ? oF : oP;
    const int m0w = blockIdx.x * 128 + wv * 32;
    const int c0 = blockIdx.y * 64;
    const int koff = (lane >> 4) * 8;
    f32x4 acc[2][4];
#pragma unroll
    for (int m = 0; m < 2; ++m)
#pragma unroll
        for (int s = 0; s < 4; ++s) acc[m][s] = f32x4{0.f, 0.f, 0.f, 0.f};

    const float* xp0 = x + (size_t)(m0w + (lane & 15)) * Dd + koff;
#pragma unroll
    for (int kc = 0; kc < 4; ++kc) {
        bf16x8 a0, a1;
        {
            float4 f0 = *(const float4*)(xp0 + kc * 32);
            float4 f1 = *(const float4*)(xp0 + kc * 32 + 4);
            a0[0] = (bf16)f0.x; a0[1] = (bf16)f0.y; a0[2] = (bf16)f0.z; a0[3] = (bf16)f0.w;
            a0[4] = (bf16)f1.x; a0[5] = (bf16)f1.y; a0[6] = (bf16)f1.z; a0[7] = (bf16)f1.w;
            float4 g0 = *(const float4*)(xp0 + 16 * Dd + kc * 32);
            float4 g1 = *(const float4*)(xp0 + 16 * Dd + kc * 32 + 4);
            a1[0] = (bf16)g0.x; a1[1] = (bf16)g0.y; a1[2] = (bf16)g0.z; a1[3] = (bf16)g0.w;
            a1[4] = (bf16)g1.x; a1[5] = (bf16)g1.y; a1[6] = (bf16)g1.z; a1[7] = (bf16)g1.w;
        }
#pragma unroll
        for (int s = 0; s < 4; ++s) {
            bf16x8 b = *(const bf16x8*)(WT + (size_t)(c0 + s * 16 + (lane & 15)) * Dd + kc * 32 + koff);
            acc[0][s] = __builtin_amdgcn_mfma_f32_16x16x32_bf16(a0, b, acc[0][s], 0, 0, 0);
            acc[1][s] = __builtin_amdgcn_mfma_f32_16x16x32_bf16(a1, b, acc[1][s], 0, 0, 0);
        }
    }
#pragma unroll
    for (int m = 0; m < 2; ++m)
#pragma unroll
        for (int s = 0; s < 4; ++s) {
            int col = c0 + s * 16 + (lane & 15);
            float bv = bias[col];
#pragma unroll
            for (int r = 0; r < 4; ++r) {
                int row = m0w + m * 16 + (lane >> 4) * 4 + r;
                o[(size_t)row * Ee + col] = (bf16)fmaxf(acc[m][s][r] + bv, 0.0f);
            }
        }
}

// ---------------- persistent cooperative GRU, v3: B-in-registers, h staged in LDS ----------------
// 256 blocks = 32 row-groups (im, 32 rows) x 8 col-blocks (in, 64 cols). im = bid&31 -> group
// pinned to XCD im&7. 6 waves/block: g = wv>>1 (gate r/z/n), cn = wv&1 (col half, 32).
// Wave GEMM tile: 32 rows x 32 cols, gate g, via mfma 32x32x16; B frags live in VGPRs.
// h for the step is staged once into LDS (32 KB, XOR-swizzled) -> 8 MB/step L3 traffic total.
// Gate pre-activations combined through small LDS planes; n-gate keeps xn/hn separate.
__global__ __launch_bounds__(384, 2) void k_gru_all(
    const bf16* __restrict__ embP, const bf16* __restrict__ embF, const float* __restrict__ noise,
    const bf16* __restrict__ WihE, const bf16* __restrict__ WhhE,
    const float* __restrict__ bIhE, const float* __restrict__ bHhE,
    const bf16* __restrict__ WihD, const bf16* __restrict__ WhhD,
    const float* __restrict__ bIhD, const float* __restrict__ bHhD,
    bf16* __restrict__ hA, bf16* __restrict__ hB, bf16* __restrict__ ys, unsigned* __restrict__ flags) {
    __shared__ bf16 hS[32 * 512];        // 32 KB staged h (rows XOR-swizzled in k)
    __shared__ float gS[4][32][68];      // gate planes: r, z, nx, nh (padded rows)
    __shared__ float bT[64][4];          // per-col bias table {br, bz, bin, bhn}

    const int tid = threadIdx.x;
    const int lane = tid & 63, wv = tid >> 6;   // wv 0..5
    const int bid = blockIdx.x;
    const int im = bid & 31;                    // row group; xcd = im&7
    const int in = bid >> 5;                    // col block 0..7
    const int g = wv >> 1;                      // 0=r,1=z,2=n
    const int cn = wv & 1;
    const int colT = in * 64 + cn * 32;
    const int l31 = lane & 31, l5 = lane >> 5;
    const int rowg0 = im * 32;
    const unsigned rx = (unsigned)((l31 & 15) << 4);

    unsigned* fbase = flags + (size_t)im * 8 * 16;   // 8 peer flags, 64B apart

    // ---- B fragments in registers (gate g, cols colT..+32) ----
    bf16x8 Bx[16], Bh[32];
    auto load_B = [&](const bf16* WihT, const bf16* WhhT) {
        const bf16* px = WihT + (size_t)(g * Hh + colT + l31) * Ee + l5 * 8;
#pragma unroll
        for (int kf = 0; kf < 16; ++kf) Bx[kf] = *(const bf16x8*)(px + kf * 16);
        const bf16* ph = WhhT + (size_t)(g * Hh + colT + l31) * Hh + l5 * 8;
#pragma unroll
        for (int kf = 0; kf < 32; ++kf) Bh[kf] = *(const bf16x8*)(ph + kf * 16);
    };

    auto build_bias = [&](const float* bIh, const float* bHh) {
        for (int c = tid; c < 64; c += 384) {
            int col = in * 64 + c;
            bT[c][0] = bIh[col] + bHh[col];
            bT[c][1] = bIh[Hh + col] + bHh[Hh + col];
            bT[c][2] = bIh[2 * Hh + col];
            bT[c][3] = bHh[2 * Hh + col];
        }
    };

    // ---- sync primitives ----
    auto signal = [&](unsigned seq) {
        asm volatile("s_waitcnt vmcnt(0)" ::: "memory");
        __syncthreads();
        if (tid == 0) {
            unsigned* fp = fbase + in * 16;
            asm volatile("global_store_dword %0, %1, off sc1" :: "v"(fp), "v"(seq) : "memory");
        }
    };
    auto wait_all = [&](unsigned seq) {
        const unsigned* fp = fbase + (lane & 7) * 16;
        for (;;) {
            unsigned v;
            asm volatile("global_load_dword %0, %1, off sc1\n\ts_waitcnt vmcnt(0)"
                         : "=v"(v) : "v"(fp) : "memory");
            if (__all((int)(v >= seq))) break;
            __builtin_amdgcn_s_sleep(2);
        }
    };

    // ---- stage h slice (32 rows x 512 cols bf16) into hS; 16 units of 2KB over 6 waves ----
    auto stage = [&](const bf16* hp, unsigned seq) {
        wait_all(seq);
        bf16x8 v[6];
#pragma unroll
        for (int u0 = 0; u0 < 3; ++u0) {
            int u = wv + u0 * 6;
            if (u < 16) {
                int p = u >> 1, hh = u & 1;
#pragma unroll
                for (int i = 0; i < 2; ++i) {
                    int idx = i * 64 + lane;
                    int r = hh * 16 + (idx >> 3), cg = idx & 7;
                    const bf16* ga = hp + (size_t)(rowg0 + r) * Hh + p * 64 + cg * 8;
                    LD_SC(v[u0 * 2 + i], ga);
                }
            }
        }
        asm volatile("s_waitcnt vmcnt(0)" ::: "memory");
#pragma unroll
        for (int u0 = 0; u0 < 3; ++u0) {
            int u = wv + u0 * 6;
            if (u < 16) {
                int p = u >> 1, hh = u & 1;
#pragma unroll
                for (int i = 0; i < 2; ++i) {
                    int idx = i * 64 + lane;
                    int r = hh * 16 + (idx >> 3), cg = idx & 7;
                    unsigned byte = ((unsigned)r << 10) + ((((unsigned)p << 7) + ((unsigned)cg << 4)) ^ ((unsigned)(r & 15) << 4));
                    *(bf16x8*)((char*)hS + byte) = v[u0 * 2 + i];
                }
            }
        }
    };

    // ---- compute phases ----
    f32x16 C0, C1;
    auto zacc = [&]() {
#pragma unroll
        for (int i = 0; i < 16; ++i) { C0[i] = 0.f; C1[i] = 0.f; }
    };
    auto xp_phase = [&](const bf16* xp) {
        const bf16* ap = xp + (size_t)(rowg0 + l31) * Ee + l5 * 8;
#pragma unroll
        for (int kf = 0; kf < 16; ++kf) {
            bf16x8 a = *(const bf16x8*)(ap + kf * 16);
            C0 = __builtin_amdgcn_mfma_f32_32x32x16_bf16(a, Bx[kf], C0, 0, 0, 0);
        }
    };
    auto hw_phase = [&]() {
        const unsigned rb = (unsigned)(l31 << 10);
        if (g == 2) {
#pragma unroll
            for (int kf = 0; kf < 32; ++kf) {
                unsigned off = rb + (((unsigned)(kf * 32 + (l5 << 4))) ^ rx);
                bf16x8 a = *(const bf16x8*)((const char*)hS + off);
                C1 = __builtin_amdgcn_mfma_f32_32x32x16_bf16(a, Bh[kf], C1, 0, 0, 0);
            }
        } else {
#pragma unroll
            for (int kf = 0; kf < 32; ++kf) {
                unsigned off = rb + (((unsigned)(kf * 32 + (l5 << 4))) ^ rx);
                bf16x8 a = *(const bf16x8*)((const char*)hS + off);
                C0 = __builtin_amdgcn_mfma_f32_32x32x16_bf16(a, Bh[kf], C0, 0, 0, 0);
            }
        }
    };
    auto plane_write = [&]() {
#pragma unroll
        for (int i = 0; i < 16; ++i) {
            int row = (i & 3) + 8 * (i >> 2) + 4 * l5;
            gS[g][row][cn * 32 + l31] = C0[i];
            if (g == 2) gS[3][row][cn * 32 + l31] = C1[i];
        }
    };

    // ---- epilogue: waves 0..3, each an 8-row stripe x 64 cols; 8 outputs/lane ----
    float hreg[8];
#pragma unroll
    for (int i = 0; i < 8; ++i) hreg[i] = 0.0f;
    const int erow = wv * 8 + (lane >> 3);      // valid for wv<4
    const int cb = (lane & 7) * 8;

    auto epi = [&](bf16* op) {
        float4 R0 = *(const float4*)&gS[0][erow][cb], R1 = *(const float4*)&gS[0][erow][cb + 4];
        float4 Z0 = *(const float4*)&gS[1][erow][cb], Z1 = *(const float4*)&gS[1][erow][cb + 4];
        float4 X0 = *(const float4*)&gS[2][erow][cb], X1 = *(const float4*)&gS[2][erow][cb + 4];
        float4 H0 = *(const float4*)&gS[3][erow][cb], H1 = *(const float4*)&gS[3][erow][cb + 4];
        bf16x8 o;
#pragma unroll
        for (int j = 0; j < 8; ++j) {
            float pr = (j < 4) ? R0[j & 3] : R1[j & 3];
            float pz = (j < 4) ? Z0[j & 3] : Z1[j & 3];
            float px = (j < 4) ? X0[j & 3] : X1[j & 3];
            float ph = (j < 4) ? H0[j & 3] : H1[j & 3];
            float4 bt = *(const float4*)&bT[cb + j][0];
            float rg = sigmf(pr + bt.x);
            float zg = sigmf(pz + bt.y);
            float ng = tanhfast(px + bt.z + rg * (ph + bt.w));
            float hv = (1.0f - zg) * ng + zg * hreg[j];
            hreg[j] = hv;
            o[j] = (bf16)hv;
        }
        bf16* sp = op + (size_t)(rowg0 + erow) * Hh + in * 64 + cb;
        ST_SCX4(sp, o);
    };

    // ================= encoder =================
    load_B(WihE, WhhE);
    build_bias(bIhE, bHhE);

#pragma unroll 1
    for (int t = 0; t < Tt; ++t) {
        if (t > 0) stage((t & 1) ? hB : hA, (unsigned)t);   // h_t lives in hbuf[t&1]
        __syncthreads();
        zacc();
        xp_phase(embP + (size_t)t * Bb * Ee);
        if (t > 0) hw_phase();
        plane_write();
        __syncthreads();
        if (wv < 4) epi(((t + 1) & 1) ? hB : hA);           // h_{t+1} -> hbuf[(t+1)&1]
        signal((unsigned)(t + 1));                          // seq 1..64
    }

    // ================= hidden = h_enc + noise; switch weights =================
    wait_all((unsigned)Tt);   // peers staged h_63 (from hB) -> safe to overwrite hB
    if (wv < 4) {
        const float* np = noise + (size_t)(rowg0 + erow) * Hh + in * 64 + cb;
        float4 n0 = *(const float4*)np;
        float4 n1 = *(const float4*)(np + 4);
        bf16x8 o;
#pragma unroll
        for (int j = 0; j < 8; ++j) {
            float v = hreg[j] + ((j < 4) ? n0[j & 3] : n1[j & 3]);
            hreg[j] = v;
            o[j] = (bf16)v;
        }
        bf16* sp = hB + (size_t)(rowg0 + erow) * Hh + in * 64 + cb;
        ST_SCX4(sp, o);
    }
    load_B(WihD, WhhD);
    build_bias(bIhD, bHhD);
    signal((unsigned)(Tt + 1));   // seq 65: hmid (hB) visible

    // ================= decoder; ys[t] doubles as the bf16 hidden chain =================
#pragma unroll 1
    for (int t = 0; t < Tt; ++t) {
        stage(t ? ys + (size_t)(t - 1) * Bb * Hh : hB, (unsigned)(Tt + 1 + t));  // seq 65+t
        __syncthreads();
        zacc();
        if (t > 0) xp_phase(embF + (size_t)(t - 1) * Bb * Ee);
        hw_phase();
        plane_write();
        __syncthreads();
        if (wv < 4) epi(ys + (size_t)t * Bb * Hh);
        if (t < Tt - 1) signal((unsigned)(Tt + 2 + t));     // seq 66..128
    }
}

// ---------------- out = ys @ W_out + b_out; 64 rows/wave ----------------
__global__ __launch_bounds__(256) void k_out(const bf16* __restrict__ ys, const bf16* __restrict__ WT,
                                             const float* __restrict__ bias, float* __restrict__ out) {
    const int lane = threadIdx.x & 63, wv = threadIdx.x >> 6;
    const int m0w = blockIdx.x * 256 + wv * 64;
    const int c0 = blockIdx.y * 64;
    const int koff = (lane >> 4) * 8;
    f32x4 acc[4][4];
#pragma unroll
    for (int m = 0; m < 4; ++m)
#pragma unroll
        for (int s = 0; s < 4; ++s) acc[m][s] = f32x4{0.f, 0.f, 0.f, 0.f};

    const bf16* ap = ys + (size_t)(m0w + (lane & 15)) * Hh + koff;
#pragma unroll
    for (int kc = 0; kc < 16; ++kc) {
        bf16x8 a0 = *(const bf16x8*)(ap + kc * 32);
        bf16x8 a1 = *(const bf16x8*)(ap + 16 * Hh + kc * 32);
        bf16x8 a2 = *(const bf16x8*)(ap + 32 * Hh + kc * 32);
        bf16x8 a3 = *(const bf16x8*)(ap + 48 * Hh + kc * 32);
#pragma unroll
        for (int s = 0; s < 4; ++s) {
            bf16x8 b = *(const bf16x8*)(WT + (size_t)(c0 + s * 16 + (lane & 15)) * Hh + kc * 32 + koff);
            acc[0][s] = __builtin_amdgcn_mfma_f32_16x16x32_bf16(a0, b, acc[0][s], 0, 0, 0);
            acc[1][s] = __builtin_amdgcn_mfma_f32_16x16x32_bf16(a1, b, acc[1][s], 0, 0, 0);
            acc[2][s] = __builtin_amdgcn_mfma_f32_16x16x32_bf16(a2, b, acc[2][s], 0, 0, 0);
            acc[3][s] = __builtin_amdgcn_mfma_f32_16x16x32_bf16(a3, b, acc[3][s], 0, 0, 0);
        }
    }
#pragma unroll
    for (int m = 0; m < 4; ++m)
#pragma unroll
        for (int s = 0; s < 4; ++s) {
            int col = c0 + s * 16 + (lane & 15);
            float bv = bias[col];
#pragma unroll
            for (int r = 0; r < 4; ++r) {
                int row = m0w + m * 16 + (lane >> 4) * 4 + r;
                out[(size_t)row * Dd + col] = acc[m][s][r] + bv;
            }
        }
}

extern "C" void kernel_launch(void* const* d_in, const int* in_sizes, int n_in,
                              void* d_out, int out_size, void* d_ws, size_t ws_size,
                              hipStream_t stream) {
    const float* past = (const float*)d_in[0];
    const float* fut = (const float*)d_in[1];
    const float* noise = (const float*)d_in[2];
    const float* W_emb = (const float*)d_in[3];
    const float* b_emb = (const float*)d_in[4];
    const float* W_ih_enc = (const float*)d_in[5];
    const float* W_hh_enc = (const float*)d_in[6];
    const float* b_ih_enc = (const float*)d_in[7];
    const float* b_hh_enc = (const float*)d_in[8];
    const float* W_ih_dec = (const float*)d_in[9];
    const float* W_hh_dec = (const float*)d_in[10];
    const float* b_ih_dec = (const float*)d_in[11];
    const float* b_hh_dec = (const float*)d_in[12];
    const float* W_out = (const float*)d_in[13];
    const float* b_out = (const float*)d_in[14];
    float* out = (float*)d_out;

    char* w = (char*)d_ws;
    auto alloc = [&](size_t bytes) {
        char* p = w;
        w += (bytes + 255) & ~(size_t)255;
        return p;
    };
    bf16* embP = (bf16*)alloc((size_t)Tt * Bb * Ee * 2);
    bf16* embF = (bf16*)alloc((size_t)Tt * Bb * Ee * 2);
    bf16* ys = (bf16*)alloc((size_t)Tt * Bb * Hh * 2);
    bf16* hA = (bf16*)alloc((size_t)Bb * Hh * 2);
    bf16* hB = (bf16*)alloc((size_t)Bb * Hh * 2);
    bf16* WembT = (bf16*)alloc((size_t)Ee * Dd * 2);
    bf16* WihEncT = (bf16*)alloc((size_t)H3 * Ee * 2);
    bf16* WhhEncT = (bf16*)alloc((size_t)H3 * Hh * 2);
    bf16* WihDecT = (bf16*)alloc((size_t)H3 * Ee * 2);
    bf16* WhhDecT = (bf16*)alloc((size_t)H3 * Hh * 2);
    bf16* WoutT = (bf16*)alloc((size_t)Dd * Hh * 2);
    unsigned* flags = (unsigned*)alloc(32 * 8 * 16 * sizeof(unsigned));  // [im][peer], 64B stride

    // weight prep (all six transposes fused)
    k_prep<<<9600, 256, 0, stream>>>(W_emb, W_ih_enc, W_hh_enc, W_ih_dec, W_hh_dec, W_out,
                                     WembT, WihEncT, WhhEncT, WihDecT, WhhDecT, WoutT);

    // embeddings (past + future fused)
    k_embed<<<dim3(Tt * Bb / 128, Ee / 64, 2), 256, 0, stream>>>(past, fut, WembT, b_emb, embP, embF);

    // reset sequence flags
    hipMemsetAsync(flags, 0, 32 * 8 * 16 * sizeof(unsigned), stream);

    // cooperative persistent recurrent kernel: 256 blocks x 384 threads
    void* args[] = {(void*)&embP, (void*)&embF, (void*)&noise,
                    (void*)&WihEncT, (void*)&WhhEncT, (void*)&b_ih_enc, (void*)&b_hh_enc,
                    (void*)&WihDecT, (void*)&WhhDecT, (void*)&b_ih_dec, (void*)&b_hh_dec,
                    (void*)&hA, (void*)&hB, (void*)&ys, (void*)&flags};
    hipLaunchCooperativeKernel((const void*)k_gru_all, dim3(256), dim3(384), args, 0, stream);

    // output projection
    k_out<<<dim3(Tt * Bb / 256, Dd / 64), 256, 0, stream>>>(ys, WoutT, b_out, out);
}

// Round 8
// 2519.219 us; speedup vs baseline: 1.1618x; 1.1618x over previous
//
#include <hip/hip_runtime.h>

typedef __bf16 bf16;
typedef __bf16 bf16x8 __attribute__((ext_vector_type(8)));
typedef float f32x4 __attribute__((ext_vector_type(4)));

#define Tt 64
#define Bb 1024
#define Dd 128
#define Ee 256
#define Hh 512
#define H3 1536

__device__ __forceinline__ float sigmf(float x) { return 1.0f / (1.0f + __expf(-x)); }
__device__ __forceinline__ float tanhfast(float x) {
    float e = __expf(2.0f * x);
    return 1.0f - 2.0f / (e + 1.0f);
}

// agent-scope (device-coherent) store: write-through to L3, no dirty L2 lines.
#define ST_SC(bp, OFF, val) \
    asm volatile("global_store_short %0, %1, off offset:" #OFF " sc1" :: "v"(bp), "v"(val))

// ---------------- fused weight prep: f32 [K][N] -> bf16 [N][K] for all 6 weights ----------------
__global__ void k_prep(const float* __restrict__ We, const float* __restrict__ Wie, const float* __restrict__ Whe,
                       const float* __restrict__ Wid, const float* __restrict__ Whd, const float* __restrict__ Wo,
                       bf16* __restrict__ dWe, bf16* __restrict__ dWie, bf16* __restrict__ dWhe,
                       bf16* __restrict__ dWid, bf16* __restrict__ dWhd, bf16* __restrict__ dWo) {
    long i = (long)blockIdx.x * 256 + threadIdx.x;
    const float* s;
    bf16* d;
    int K, N;
    if (i < 32768) { s = We; d = dWe; K = Dd; N = Ee; }
    else if ((i -= 32768) < 393216) { s = Wie; d = dWie; K = Ee; N = H3; }
    else if ((i -= 393216) < 786432) { s = Whe; d = dWhe; K = Hh; N = H3; }
    else if ((i -= 786432) < 393216) { s = Wid; d = dWid; K = Ee; N = H3; }
    else if ((i -= 393216) < 786432) { s = Whd; d = dWhd; K = Hh; N = H3; }
    else if ((i -= 786432) < 65536) { s = Wo; d = dWo; K = Hh; N = Dd; }
    else return;
    int n = (int)(i / K), k = (int)(i - (long)n * K);
    d[i] = (bf16)s[(size_t)k * N + n];
}

// ---------------- embed: relu(x @ W_emb + b); past (z=0) and future (z=1) fused ----------------
__global__ __launch_bounds__(256) void k_embed(const float* __restrict__ xP, const float* __restrict__ xF,
                                               const bf16* __restrict__ WT, const float* __restrict__ bias,
                                               bf16* __restrict__ oP, bf16* __restrict__ oF) {
    const int lane = threadIdx.x & 63, wv = threadIdx.x >> 6;
    const float* x = blockIdx.z ? xF : xP;
    bf16* o = blockIdx.z ? oF : oP;
    const int m0w = blockIdx.x * 128 + wv * 32;
    const int c0 = blockIdx.y * 64;
    const int koff = (lane >> 4) * 8;
    f32x4 acc[2][4];
#pragma unroll
    for (int m = 0; m < 2; ++m)
#pragma unroll
        for (int s = 0; s < 4; ++s) acc[m][s] = f32x4{0.f, 0.f, 0.f, 0.f};

    const float* xp0 = x + (size_t)(m0w + (lane & 15)) * Dd + koff;
#pragma unroll
    for (int kc = 0; kc < 4; ++kc) {
        bf16x8 a0, a1;
        {
            float4 f0 = *(const float4*)(xp0 + kc * 32);
            float4 f1 = *(const float4*)(xp0 + kc * 32 + 4);
            a0[0] = (bf16)f0.x; a0[1] = (bf16)f0.y; a0[2] = (bf16)f0.z; a0[3] = (bf16)f0.w;
            a0[4] = (bf16)f1.x; a0[5] = (bf16)f1.y; a0[6] = (bf16)f1.z; a0[7] = (bf16)f1.w;
            float4 g0 = *(const float4*)(xp0 + 16 * Dd + kc * 32);
            float4 g1 = *(const float4*)(xp0 + 16 * Dd + kc * 32 + 4);
            a1[0] = (bf16)g0.x; a1[1] = (bf16)g0.y; a1[2] = (bf16)g0.z; a1[3] = (bf16)g0.w;
            a1[4] = (bf16)g1.x; a1[5] = (bf16)g1.y; a1[6] = (bf16)g1.z; a1[7] = (bf16)g1.w;
        }
#pragma unroll
        for (int s = 0; s < 4; ++s) {
            bf16x8 b = *(const bf16x8*)(WT + (size_t)(c0 + s * 16 + (lane & 15)) * Dd + kc * 32 + koff);
            acc[0][s] = __builtin_amdgcn_mfma_f32_16x16x32_bf16(a0, b, acc[0][s], 0, 0, 0);
            acc[1][s] = __builtin_amdgcn_mfma_f32_16x16x32_bf16(a1, b, acc[1][s], 0, 0, 0);
        }
    }
#pragma unroll
    for (int m = 0; m < 2; ++m)
#pragma unroll
        for (int s = 0; s < 4; ++s) {
            int col = c0 + s * 16 + (lane & 15);
            float bv = bias[col];
#pragma unroll
            for (int r = 0; r < 4; ++r) {
                int row = m0w + m * 16 + (lane >> 4) * 4 + r;
                o[(size_t)row * Ee + col] = (bf16)fmaxf(acc[m][s][r] + bv, 0.0f);
            }
        }
}

// ---------------- persistent cooperative GRU: wave-free-running + L2-shared h reads ----------------
// 256 blocks = 16 groups (im) x 16 col-blocks (in); XCD-affine remap pins each group to one XCD.
// 8 waves/block: rh = wv>>1 (16-row slice), ch = wv&1 (16-col half).
// Sync domain = (im, rh): 32 waves. Producers: sc1 write-through h stores + vmcnt + sc1 flag.
// Consumers: wait ALL 32 domain flags -> agent acquire fence (buffer_inv, no wb needed since
// nothing is dirty) -> PLAIN CACHED h loads. The 16 col-blocks of a group share one XCD, so the
// h slice is fetched from L3 once per XCD (MSHR-merged) and the 32x re-reads hit L2/L1.
__global__ __launch_bounds__(512, 1) void k_gru_all(
    const bf16* __restrict__ embP, const bf16* __restrict__ embF, const float* __restrict__ noise,
    const bf16* __restrict__ WihE, const bf16* __restrict__ WhhE,
    const float* __restrict__ bIhE, const float* __restrict__ bHhE,
    const bf16* __restrict__ WihD, const bf16* __restrict__ WhhD,
    const float* __restrict__ bIhD, const float* __restrict__ bHhD,
    bf16* __restrict__ hA, bf16* __restrict__ hB, bf16* __restrict__ ys, unsigned* __restrict__ flags) {
    __shared__ bf16 Wih[6 * 8 * 64 * 8];    // 49152 B
    __shared__ bf16 Whh[6 * 16 * 64 * 8];   // 98304 B
    const int tid = threadIdx.x;
    const int lane = tid & 63, wv = tid >> 6;
    // XCD-affine remap: under round-robin placement (xcd = bid & 7), each group (im)
    // lands entirely on one XCD -> h + emb reads are L2-local. Correct regardless.
    const int bid = blockIdx.x;
    const int im = (bid & 7) * 2 + (bid >> 7);
    const int in = (bid >> 3) & 15;
    const int rh = wv >> 1, ch = wv & 1;
    const int rowb = im * 64 + rh * 16;
    const int arow0 = rowb + (lane & 15);
    const int koff = (lane >> 4) * 8;
    const int colc = in * 32 + ch * 16 + (lane & 15);
    unsigned* dom = flags + ((size_t)im * 4 + rh) * 32;  // 32 flags x 4B = 128B
    const int myidx = in * 2 + ch;

    const bf16x8* WihV = (const bf16x8*)Wih;
    const bf16x8* WhhV = (const bf16x8*)Whh;

    auto stage = [&](const bf16* WT, int Kdim, int KC, bf16* lds) {
        int total = 6 * KC * 64;
        for (int idx = tid; idx < total; idx += 512) {
            int ln = idx & 63;
            int kc = (idx >> 6) % KC;
            int s = (idx >> 6) / KC;
            int gate = s >> 1, f = s & 1;
            int col = gate * Hh + in * 32 + f * 16 + (ln & 15);
            int k = kc * 32 + (ln >> 4) * 8;
            *(bf16x8*)(lds + (size_t)idx * 8) = *(const bf16x8*)(WT + (size_t)col * Kdim + k);
        }
    };

    float bi[3], bh[3];
    auto load_bias = [&](const float* bIh, const float* bHh) {
#pragma unroll
        for (int g = 0; g < 3; ++g) {
            bi[g] = bIh[g * Hh + colc];
            bh[g] = bHh[g * Hh + colc];
        }
    };

    // per-WAVE release: my stores acked (at L3) -> lane0 publishes seq. No block barrier.
    auto signal = [&](unsigned seq) {
        asm volatile("s_waitcnt vmcnt(0)" ::: "memory");
        if (lane == 0) {
            unsigned* fp = dom + myidx;
            asm volatile("global_store_dword %0, %1, off sc1" :: "v"(fp), "v"(seq) : "memory");
        }
    };
    // acquire: all 32 domain flags >= seq (lane k polls flag k&31), then invalidate caches.
    auto wait_acquire = [&](unsigned seq) {
        const unsigned* fp = dom + (lane & 31);
        for (;;) {
            unsigned v;
            asm volatile("global_load_dword %0, %1, off sc1\n\ts_waitcnt vmcnt(0)"
                         : "=v"(v) : "v"(fp) : "memory");
            if (__all((int)(v >= seq))) break;
            __builtin_amdgcn_s_sleep(1);
        }
        __builtin_amdgcn_fence(__ATOMIC_ACQUIRE, "agent");  // buffer_inv: fresh L1/L2
        __builtin_amdgcn_sched_barrier(0);
    };

    f32x4 aR, aZ, aNX, aNH;
    auto zacc = [&]() {
        aR = f32x4{0.f, 0.f, 0.f, 0.f};
        aZ = f32x4{0.f, 0.f, 0.f, 0.f};
        aNX = f32x4{0.f, 0.f, 0.f, 0.f};
        aNH = f32x4{0.f, 0.f, 0.f, 0.f};
    };

    auto xp_phase = [&](const bf16* xp) {
        const bf16* ap = xp + (size_t)arow0 * Ee + koff;
#pragma unroll
        for (int kc = 0; kc < 8; ++kc) {
            bf16x8 a = *(const bf16x8*)(ap + kc * 32);
            aR = __builtin_amdgcn_mfma_f32_16x16x32_bf16(a, WihV[((0 + ch) * 8 + kc) * 64 + lane], aR, 0, 0, 0);
            aZ = __builtin_amdgcn_mfma_f32_16x16x32_bf16(a, WihV[((2 + ch) * 8 + kc) * 64 + lane], aZ, 0, 0, 0);
            aNX = __builtin_amdgcn_mfma_f32_16x16x32_bf16(a, WihV[((4 + ch) * 8 + kc) * 64 + lane], aNX, 0, 0, 0);
        }
    };

    // hW: wait all peers -> acquire fence -> plain cached loads (L2-shared within the XCD).
    auto hw_phase = [&](const bf16* hp, unsigned seq) {
        wait_acquire(seq);
        const bf16* ap = hp + (size_t)arow0 * Hh + koff;
        bf16x8 h0[16];
#pragma unroll
        for (int kc = 0; kc < 16; ++kc) h0[kc] = *(const bf16x8*)(ap + kc * 32);
#pragma unroll
        for (int kc = 0; kc < 16; ++kc) {
            aR = __builtin_amdgcn_mfma_f32_16x16x32_bf16(h0[kc], WhhV[((0 + ch) * 16 + kc) * 64 + lane], aR, 0, 0, 0);
            aZ = __builtin_amdgcn_mfma_f32_16x16x32_bf16(h0[kc], WhhV[((2 + ch) * 16 + kc) * 64 + lane], aZ, 0, 0, 0);
            aNH = __builtin_amdgcn_mfma_f32_16x16x32_bf16(h0[kc], WhhV[((4 + ch) * 16 + kc) * 64 + lane], aNH, 0, 0, 0);
        }
    };

    float hreg[4];
#pragma unroll
    for (int i = 0; i < 4; ++i) hreg[i] = 0.0f;

    auto epi = [&](bf16* op) {
        bf16* stb = op + (size_t)(rowb + (lane >> 4) * 4) * Hh + colc;
        unsigned short us[4];
#pragma unroll
        for (int r = 0; r < 4; ++r) {
            float rg = sigmf(aR[r] + bi[0] + bh[0]);
            float zg = sigmf(aZ[r] + bi[1] + bh[1]);
            float ng = tanhfast(aNX[r] + bi[2] + rg * (aNH[r] + bh[2]));
            float hv = (1.0f - zg) * ng + zg * hreg[r];
            hreg[r] = hv;
            us[r] = __builtin_bit_cast(unsigned short, (bf16)hv);
        }
        ST_SC(stb, 0, us[0]);
        ST_SC(stb, 1024, us[1]);
        ST_SC(stb, 2048, us[2]);
        ST_SC(stb, 3072, us[3]);
    };

    // ---------- encoder ----------
    stage(WihE, Ee, 8, Wih);
    stage(WhhE, Hh, 16, Whh);
    load_bias(bIhE, bHhE);
    __syncthreads();

#pragma unroll 1
    for (int t = 0; t < Tt; ++t) {
        zacc();
        xp_phase(embP + (size_t)t * Bb * Ee);
        if (t > 0) hw_phase(((t - 1) & 1) ? hB : hA, (unsigned)t);
        epi((t & 1) ? hB : hA);
        signal((unsigned)(t + 1));  // seq 1..64
    }

    // ---------- hidden = h_enc + noise; switch to decoder weights ----------
    wait_acquire((unsigned)Tt);  // rh-domain peers done reading hA (enc step 63)
    {
        bf16* stb = hA + (size_t)(rowb + (lane >> 4) * 4) * Hh + colc;
        unsigned short us[4];
#pragma unroll
        for (int r = 0; r < 4; ++r) {
            int row = rowb + (lane >> 4) * 4 + r;
            float v = hreg[r] + noise[(size_t)row * Hh + colc];
            hreg[r] = v;
            us[r] = __builtin_bit_cast(unsigned short, (bf16)v);
        }
        ST_SC(stb, 0, us[0]);
        ST_SC(stb, 1024, us[1]);
        ST_SC(stb, 2048, us[2]);
        ST_SC(stb, 3072, us[3]);
    }
    __syncthreads();  // all waves of this block past their enc LDS reads
    stage(WihD, Ee, 8, Wih);
    stage(WhhD, Hh, 16, Whh);
    __syncthreads();  // decoder LDS staged before any wave's dec reads
    load_bias(bIhD, bHhD);
    signal((unsigned)(Tt + 1));  // seq 65: hA(+noise) visible

    // ---------- decoder; ys[t] doubles as the bf16 hidden chain ----------
#pragma unroll 1
    for (int t = 0; t < Tt; ++t) {
        zacc();
        if (t > 0) xp_phase(embF + (size_t)(t - 1) * Bb * Ee);
        hw_phase(t ? ys + (size_t)(t - 1) * Bb * Hh : hA, (unsigned)(Tt + 1 + t));  // seq 65+t
        epi(ys + (size_t)t * Bb * Hh);
        if (t < Tt - 1) signal((unsigned)(Tt + 2 + t));  // seq 66..128
    }
}

// ---------------- out = ys @ W_out + b_out; 64 rows/wave ----------------
__global__ __launch_bounds__(256) void k_out(const bf16* __restrict__ ys, const bf16* __restrict__ WT,
                                             const float* __restrict__ bias, float* __restrict__ out) {
    const int lane = threadIdx.x & 63, wv = threadIdx.x >> 6;
    const int m0w = blockIdx.x * 256 + wv * 64;
    const int c0 = blockIdx.y * 64;
    const int koff = (lane >> 4) * 8;
    f32x4 acc[4][4];
#pragma unroll
    for (int m = 0; m < 4; ++m)
#pragma unroll
        for (int s = 0; s < 4; ++s) acc[m][s] = f32x4{0.f, 0.f, 0.f, 0.f};

    const bf16* ap = ys + (size_t)(m0w + (lane & 15)) * Hh + koff;
#pragma unroll
    for (int kc = 0; kc < 16; ++kc) {
        bf16x8 a0 = *(const bf16x8*)(ap + kc * 32);
        bf16x8 a1 = *(const bf16x8*)(ap + 16 * Hh + kc * 32);
        bf16x8 a2 = *(const bf16x8*)(ap + 32 * Hh + kc * 32);
        bf16x8 a3 = *(const bf16x8*)(ap + 48 * Hh + kc * 32);
#pragma unroll
        for (int s = 0; s < 4; ++s) {
            bf16x8 b = *(const bf16x8*)(WT + (size_t)(c0 + s * 16 + (lane & 15)) * Hh + kc * 32 + koff);
            acc[0][s] = __builtin_amdgcn_mfma_f32_16x16x32_bf16(a0, b, acc[0][s], 0, 0, 0);
            acc[1][s] = __builtin_amdgcn_mfma_f32_16x16x32_bf16(a1, b, acc[1][s], 0, 0, 0);
            acc[2][s] = __builtin_amdgcn_mfma_f32_16x16x32_bf16(a2, b, acc[2][s], 0, 0, 0);
            acc[3][s] = __builtin_amdgcn_mfma_f32_16x16x32_bf16(a3, b, acc[3][s], 0, 0, 0);
        }
    }
#pragma unroll
    for (int m = 0; m < 4; ++m)
#pragma unroll
        for (int s = 0; s < 4; ++s) {
            int col = c0 + s * 16 + (lane & 15);
            float bv = bias[col];
#pragma unroll
            for (int r = 0; r < 4; ++r) {
                int row = m0w + m * 16 + (lane >> 4) * 4 + r;
                out[(size_t)row * Dd + col] = acc[m][s][r] + bv;
            }
        }
}

extern "C" void kernel_launch(void* const* d_in, const int* in_sizes, int n_in,
                              void* d_out, int out_size, void* d_ws, size_t ws_size,
                              hipStream_t stream) {
    const float* past = (const float*)d_in[0];
    const float* fut = (const float*)d_in[1];
    const float* noise = (const float*)d_in[2];
    const float* W_emb = (const float*)d_in[3];
    const float* b_emb = (const float*)d_in[4];
    const float* W_ih_enc = (const float*)d_in[5];
    const float* W_hh_enc = (const float*)d_in[6];
    const float* b_ih_enc = (const float*)d_in[7];
    const float* b_hh_enc = (const float*)d_in[8];
    const float* W_ih_dec = (const float*)d_in[9];
    const float* W_hh_dec = (const float*)d_in[10];
    const float* b_ih_dec = (const float*)d_in[11];
    const float* b_hh_dec = (const float*)d_in[12];
    const float* W_out = (const float*)d_in[13];
    const float* b_out = (const float*)d_in[14];
    float* out = (float*)d_out;

    char* w = (char*)d_ws;
    auto alloc = [&](size_t bytes) {
        char* p = w;
        w += (bytes + 255) & ~(size_t)255;
        return p;
    };
    bf16* embP = (bf16*)alloc((size_t)Tt * Bb * Ee * 2);
    bf16* embF = (bf16*)alloc((size_t)Tt * Bb * Ee * 2);
    bf16* ys = (bf16*)alloc((size_t)Tt * Bb * Hh * 2);
    bf16* hA = (bf16*)alloc((size_t)Bb * Hh * 2);
    bf16* hB = (bf16*)alloc((size_t)Bb * Hh * 2);
    bf16* WembT = (bf16*)alloc((size_t)Ee * Dd * 2);
    bf16* WihEncT = (bf16*)alloc((size_t)H3 * Ee * 2);
    bf16* WhhEncT = (bf16*)alloc((size_t)H3 * Hh * 2);
    bf16* WihDecT = (bf16*)alloc((size_t)H3 * Ee * 2);
    bf16* WhhDecT = (bf16*)alloc((size_t)H3 * Hh * 2);
    bf16* WoutT = (bf16*)alloc((size_t)Dd * Hh * 2);
    unsigned* flags = (unsigned*)alloc(16 * 4 * 32 * sizeof(unsigned));  // [im][rh][32]

    // weight prep (all six transposes fused)
    k_prep<<<9600, 256, 0, stream>>>(W_emb, W_ih_enc, W_hh_enc, W_ih_dec, W_hh_dec, W_out,
                                     WembT, WihEncT, WhhEncT, WihDecT, WhhDecT, WoutT);

    // embeddings (past + future fused)
    k_embed<<<dim3(Tt * Bb / 128, Ee / 64, 2), 256, 0, stream>>>(past, fut, WembT, b_emb, embP, embF);

    // reset sequence flags
    hipMemsetAsync(flags, 0, 16 * 4 * 32 * sizeof(unsigned), stream);

    // cooperative persistent recurrent kernel
    void* args[] = {(void*)&embP, (void*)&embF, (void*)&noise,
                    (void*)&WihEncT, (void*)&WhhEncT, (void*)&b_ih_enc, (void*)&b_hh_enc,
                    (void*)&WihDecT, (void*)&WhhDecT, (void*)&b_ih_dec, (void*)&b_hh_dec,
                    (void*)&hA, (void*)&hB, (void*)&ys, (void*)&flags};
    hipLaunchCooperativeKernel((const void*)k_gru_all, dim3(256), dim3(512), args, 0, stream);

    // output projection
    k_out<<<dim3(Tt * Bb / 256, Dd / 64), 256, 0, stream>>>(ys, WoutT, b_out, out);
}

// Round 11
// 1004.348 us; speedup vs baseline: 2.9140x; 2.5083x over previous
//
#include <hip/hip_runtime.h>

typedef __bf16 bf16;
typedef __bf16 bf16x8 __attribute__((ext_vector_type(8)));
typedef float f32x4 __attribute__((ext_vector_type(4)));

#define Tt 64
#define Bb 1024
#define Dd 128
#define Ee 256
#define Hh 512
#define H3 1536

__device__ __forceinline__ float sigmf(float x) { return 1.0f / (1.0f + __expf(-x)); }
__device__ __forceinline__ float tanhfast(float x) {
    float e = __expf(2.0f * x);
    return 1.0f - 2.0f / (e + 1.0f);
}

// agent-scope (device-coherent) ops; sc1 = bypass L2 to the memory-side L3.
#define LD_SC(dst, bp, OFF) \
    asm volatile("global_load_dwordx4 %0, %1, off offset:" #OFF " sc1" : "=&v"(dst) : "v"(bp))
#define ST_SC(bp, OFF, val) \
    asm volatile("global_store_short %0, %1, off offset:" #OFF " sc1" :: "v"(bp), "v"(val))

// ---------------- fused weight prep: f32 [K][N] -> bf16 [N][K] for all 6 weights ----------------
__global__ void k_prep(const float* __restrict__ We, const float* __restrict__ Wie, const float* __restrict__ Whe,
                       const float* __restrict__ Wid, const float* __restrict__ Whd, const float* __restrict__ Wo,
                       bf16* __restrict__ dWe, bf16* __restrict__ dWie, bf16* __restrict__ dWhe,
                       bf16* __restrict__ dWid, bf16* __restrict__ dWhd, bf16* __restrict__ dWo) {
    long i = (long)blockIdx.x * 256 + threadIdx.x;
    const float* s;
    bf16* d;
    int K, N;
    if (i < 32768) { s = We; d = dWe; K = Dd; N = Ee; }
    else if ((i -= 32768) < 393216) { s = Wie; d = dWie; K = Ee; N = H3; }
    else if ((i -= 393216) < 786432) { s = Whe; d = dWhe; K = Hh; N = H3; }
    else if ((i -= 786432) < 393216) { s = Wid; d = dWid; K = Ee; N = H3; }
    else if ((i -= 393216) < 786432) { s = Whd; d = dWhd; K = Hh; N = H3; }
    else if ((i -= 786432) < 65536) { s = Wo; d = dWo; K = Hh; N = Dd; }
    else return;
    int n = (int)(i / K), k = (int)(i - (long)n * K);
    d[i] = (bf16)s[(size_t)k * N + n];
}

// ---------------- embed: relu(x @ W_emb + b); past (z=0) and future (z=1) fused ----------------
__global__ __launch_bounds__(256) void k_embed(const float* __restrict__ xP, const float* __restrict__ xF,
                                               const bf16* __restrict__ WT, const float* __restrict__ bias,
                                               bf16* __restrict__ oP, bf16* __restrict__ oF) {
    const int lane = threadIdx.x & 63, wv = threadIdx.x >> 6;
    const float* x = blockIdx.z ? xF : xP;
    bf16* o = blockIdx.z ? oF : oP;
    const int m0w = blockIdx.x * 128 + wv * 32;
    const int c0 = blockIdx.y * 64;
    const int koff = (lane >> 4) * 8;
    f32x4 acc[2][4];
#pragma unroll
    for (int m = 0; m < 2; ++m)
#pragma unroll
        for (int s = 0; s < 4; ++s) acc[m][s] = f32x4{0.f, 0.f, 0.f, 0.f};

    const float* xp0 = x + (size_t)(m0w + (lane & 15)) * Dd + koff;
#pragma unroll
    for (int kc = 0; kc < 4; ++kc) {
        bf16x8 a0, a1;
        {
            float4 f0 = *(const float4*)(xp0 + kc * 32);
            float4 f1 = *(const float4*)(xp0 + kc * 32 + 4);
            a0[0] = (bf16)f0.x; a0[1] = (bf16)f0.y; a0[2] = (bf16)f0.z; a0[3] = (bf16)f0.w;
            a0[4] = (bf16)f1.x; a0[5] = (bf16)f1.y; a0[6] = (bf16)f1.z; a0[7] = (bf16)f1.w;
            float4 g0 = *(const float4*)(xp0 + 16 * Dd + kc * 32);
            float4 g1 = *(const float4*)(xp0 + 16 * Dd + kc * 32 + 4);
            a1[0] = (bf16)g0.x; a1[1] = (bf16)g0.y; a1[2] = (bf16)g0.z; a1[3] = (bf16)g0.w;
            a1[4] = (bf16)g1.x; a1[5] = (bf16)g1.y; a1[6] = (bf16)g1.z; a1[7] = (bf16)g1.w;
        }
#pragma unroll
        for (int s = 0; s < 4; ++s) {
            bf16x8 b = *(const bf16x8*)(WT + (size_t)(c0 + s * 16 + (lane & 15)) * Dd + kc * 32 + koff);
            acc[0][s] = __builtin_amdgcn_mfma_f32_16x16x32_bf16(a0, b, acc[0][s], 0, 0, 0);
            acc[1][s] = __builtin_amdgcn_mfma_f32_16x16x32_bf16(a1, b, acc[1][s], 0, 0, 0);
        }
    }
#pragma unroll
    for (int m = 0; m < 2; ++m)
#pragma unroll
        for (int s = 0; s < 4; ++s) {
            int col = c0 + s * 16 + (lane & 15);
            float bv = bias[col];
#pragma unroll
            for (int r = 0; r < 4; ++r) {
                int row = m0w + m * 16 + (lane >> 4) * 4 + r;
                o[(size_t)row * Ee + col] = (bf16)fmaxf(acc[m][s][r] + bv, 0.0f);
            }
        }
}

// ---------------- persistent cooperative GRU v5: round-6 skeleton, ch folded into waves ----------------
// 256 blocks = 16 groups (im) x 16 col-blocks (in); XCD-affine remap. 4 waves/block: wv = rh
// (16-row slice). Each wave computes BOTH 16-col halves (f=0,1) of the block's 32 cols -> each
// h byte read once per (im,rh) per block: 16 MB/step (round 6: 32). MFMA 16x16x32 (proven).
// Sync domain = (im, rh): 16 block-peers, one wave each, per-wave sc1 flags, per-peer
// pipelined HSTEP waits. No per-step __syncthreads. Ledger identical to round 6.
__global__ __launch_bounds__(256, 1) void k_gru_all(
    const bf16* __restrict__ embP, const bf16* __restrict__ embF, const float* __restrict__ noise,
    const bf16* __restrict__ WihE, const bf16* __restrict__ WhhE,
    const float* __restrict__ bIhE, const float* __restrict__ bHhE,
    const bf16* __restrict__ WihD, const bf16* __restrict__ WhhD,
    const float* __restrict__ bIhD, const float* __restrict__ bHhD,
    bf16* __restrict__ hA, bf16* __restrict__ hB, bf16* __restrict__ ys, unsigned* __restrict__ flags) {
    __shared__ bf16 Wih[6 * 8 * 64 * 8];    // 49152 B: [s=gate*2+f][kc8][lane]x8
    __shared__ bf16 Whh[6 * 16 * 64 * 8];   // 98304 B: [s=gate*2+f][kc16][lane]x8
    const int tid = threadIdx.x;
    const int lane = tid & 63, rh = tid >> 6;    // rh 0..3
    const int bid = blockIdx.x;
    const int im = (bid & 7) * 2 + (bid >> 7);   // group 0..15; xcd = bid&7
    const int in = (bid >> 3) & 15;              // col block 0..15
    const int rowb = im * 64 + rh * 16;
    const int arow0 = rowb + (lane & 15);
    const int koff = (lane >> 4) * 8;
    const int colc0 = in * 32 + (lane & 15);     // f=0 column; f=1 adds 16
    unsigned* dom = flags + ((size_t)im * 4 + rh) * 16 * 16;  // 16 flags x 64B

    const bf16x8* WihV = (const bf16x8*)Wih;
    const bf16x8* WhhV = (const bf16x8*)Whh;

    auto stage = [&](const bf16* WT, int Kdim, int KC, bf16* lds) {
        int total = 6 * KC * 64;
        for (int idx = tid; idx < total; idx += 256) {
            int ln = idx & 63;
            int kc = (idx >> 6) % KC;
            int s = (idx >> 6) / KC;
            int gate = s >> 1, f = s & 1;
            int col = gate * Hh + in * 32 + f * 16 + (ln & 15);
            int k = kc * 32 + (ln >> 4) * 8;
            *(bf16x8*)(lds + (size_t)idx * 8) = *(const bf16x8*)(WT + (size_t)col * Kdim + k);
        }
    };

    float bi[3][2], bh[3][2];
    auto load_bias = [&](const float* bIh, const float* bHh) {
#pragma unroll
        for (int g = 0; g < 3; ++g)
#pragma unroll
            for (int f = 0; f < 2; ++f) {
                int c = g * Hh + colc0 + f * 16;
                bi[g][f] = bIh[c];
                bh[g][f] = bHh[c];
            }
    };

    // per-WAVE release: my sc1 stores acked at L3 -> lane0 publishes seq. No block barrier.
    auto signal = [&](unsigned seq) {
        asm volatile("s_waitcnt vmcnt(0)" ::: "memory");
        if (lane == 0) {
            unsigned* fp = dom + in * 16;
            asm volatile("global_store_dword %0, %1, off sc1" :: "v"(fp), "v"(seq) : "memory");
        }
    };
    // one poll: lane k loads peer (k&15)'s flag -> 64-bit ballot (bit p valid via lane p)
    auto poll = [&](unsigned seq) -> unsigned long long {
        unsigned v;
        const unsigned* fp = dom + (lane & 15) * 16;
        asm volatile("global_load_dword %0, %1, off sc1\n\ts_waitcnt vmcnt(0)"
                     : "=&v"(v) : "v"(fp) : "memory");
        return __ballot((int)(v >= seq));
    };
    auto wait_all = [&](unsigned seq) {
        while (poll(seq) != ~0ULL) __builtin_amdgcn_s_sleep(2);
    };

    f32x4 aR[2], aZ[2], aNX[2], aNH[2];
    auto zacc = [&]() {
#pragma unroll
        for (int f = 0; f < 2; ++f) {
            aR[f] = f32x4{0.f, 0.f, 0.f, 0.f};
            aZ[f] = f32x4{0.f, 0.f, 0.f, 0.f};
            aNX[f] = f32x4{0.f, 0.f, 0.f, 0.f};
            aNH[f] = f32x4{0.f, 0.f, 0.f, 0.f};
        }
    };

    auto xp_phase = [&](const bf16* xp) {
        const bf16* ap = xp + (size_t)arow0 * Ee + koff;
#pragma unroll
        for (int kc = 0; kc < 8; ++kc) {
            bf16x8 a = *(const bf16x8*)(ap + kc * 32);
#pragma unroll
            for (int f = 0; f < 2; ++f) {
                aR[f] = __builtin_amdgcn_mfma_f32_16x16x32_bf16(a, WihV[((0 + f) * 8 + kc) * 64 + lane], aR[f], 0, 0, 0);
                aZ[f] = __builtin_amdgcn_mfma_f32_16x16x32_bf16(a, WihV[((2 + f) * 8 + kc) * 64 + lane], aZ[f], 0, 0, 0);
                aNX[f] = __builtin_amdgcn_mfma_f32_16x16x32_bf16(a, WihV[((4 + f) * 8 + kc) * 64 + lane], aNX[f], 0, 0, 0);
            }
        }
    };

    // hW with per-peer pipelined waits: K-chunk kc=p holds peer block p's columns (flag p).
    auto hw_phase = [&](const bf16* hp, unsigned seq) {
        const bf16* h0p = hp + (size_t)arow0 * Hh + koff;
        bf16x8 h0[16];
        unsigned long long rdy = poll(seq);
#define HSTEP(p, OFF) \
        while (!((rdy >> p) & 1ULL)) { __builtin_amdgcn_s_sleep(2); rdy = poll(seq); } \
        LD_SC(h0[p], h0p, OFF);
        HSTEP(0, 0)    HSTEP(1, 64)   HSTEP(2, 128)  HSTEP(3, 192)
        HSTEP(4, 256)  HSTEP(5, 320)  HSTEP(6, 384)  HSTEP(7, 448)
        HSTEP(8, 512)  HSTEP(9, 576)  HSTEP(10, 640) HSTEP(11, 704)
        HSTEP(12, 768) HSTEP(13, 832) HSTEP(14, 896) HSTEP(15, 960)
#undef HSTEP
        asm volatile("s_waitcnt vmcnt(0)" ::: "memory");
        __builtin_amdgcn_sched_barrier(0);
#pragma unroll
        for (int kc = 0; kc < 16; ++kc) {
#pragma unroll
            for (int f = 0; f < 2; ++f) {
                aR[f] = __builtin_amdgcn_mfma_f32_16x16x32_bf16(h0[kc], WhhV[((0 + f) * 16 + kc) * 64 + lane], aR[f], 0, 0, 0);
                aZ[f] = __builtin_amdgcn_mfma_f32_16x16x32_bf16(h0[kc], WhhV[((2 + f) * 16 + kc) * 64 + lane], aZ[f], 0, 0, 0);
                aNH[f] = __builtin_amdgcn_mfma_f32_16x16x32_bf16(h0[kc], WhhV[((4 + f) * 16 + kc) * 64 + lane], aNH[f], 0, 0, 0);
            }
        }
    };

    float hreg[8];
#pragma unroll
    for (int i = 0; i < 8; ++i) hreg[i] = 0.0f;

    auto epi = [&](bf16* op) {
#pragma unroll
        for (int f = 0; f < 2; ++f) {
            bf16* stb = op + (size_t)(rowb + (lane >> 4) * 4) * Hh + colc0 + f * 16;
            unsigned short us[4];
#pragma unroll
            for (int r = 0; r < 4; ++r) {
                float rg = sigmf(aR[f][r] + bi[0][f] + bh[0][f]);
                float zg = sigmf(aZ[f][r] + bi[1][f] + bh[1][f]);
                float ng = tanhfast(aNX[f][r] + bi[2][f] + rg * (aNH[f][r] + bh[2][f]));
                float hv = (1.0f - zg) * ng + zg * hreg[f * 4 + r];
                hreg[f * 4 + r] = hv;
                us[r] = __builtin_bit_cast(unsigned short, (bf16)hv);
            }
            ST_SC(stb, 0, us[0]);
            ST_SC(stb, 1024, us[1]);
            ST_SC(stb, 2048, us[2]);
            ST_SC(stb, 3072, us[3]);
        }
    };

    // ---------- encoder ----------
    stage(WihE, Ee, 8, Wih);
    stage(WhhE, Hh, 16, Whh);
    load_bias(bIhE, bHhE);
    __syncthreads();

#pragma unroll 1
    for (int t = 0; t < Tt; ++t) {
        zacc();
        xp_phase(embP + (size_t)t * Bb * Ee);
        if (t > 0) hw_phase(((t - 1) & 1) ? hB : hA, (unsigned)t);
        epi((t & 1) ? hB : hA);
        signal((unsigned)(t + 1));  // seq 1..64
    }

    // ---------- hidden = h_enc + noise; switch to decoder weights ----------
    wait_all((unsigned)Tt);  // (im,rh) peers done with enc step 63 (incl. hA reads)
    {
#pragma unroll
        for (int f = 0; f < 2; ++f) {
            bf16* stb = hA + (size_t)(rowb + (lane >> 4) * 4) * Hh + colc0 + f * 16;
            unsigned short us[4];
#pragma unroll
            for (int r = 0; r < 4; ++r) {
                int row = rowb + (lane >> 4) * 4 + r;
                float v = hreg[f * 4 + r] + noise[(size_t)row * Hh + colc0 + f * 16];
                hreg[f * 4 + r] = v;
                us[r] = __builtin_bit_cast(unsigned short, (bf16)v);
            }
            ST_SC(stb, 0, us[0]);
            ST_SC(stb, 1024, us[1]);
            ST_SC(stb, 2048, us[2]);
            ST_SC(stb, 3072, us[3]);
        }
    }
    __syncthreads();  // all waves of this block past their enc LDS reads
    stage(WihD, Ee, 8, Wih);
    stage(WhhD, Hh, 16, Whh);
    __syncthreads();  // decoder LDS staged before any wave's dec reads
    load_bias(bIhD, bHhD);
    signal((unsigned)(Tt + 1));  // seq 65: hA(+noise) visible

    // ---------- decoder; ys[t] doubles as the bf16 hidden chain ----------
#pragma unroll 1
    for (int t = 0; t < Tt; ++t) {
        zacc();
        if (t > 0) xp_phase(embF + (size_t)(t - 1) * Bb * Ee);
        hw_phase(t ? ys + (size_t)(t - 1) * Bb * Hh : hA, (unsigned)(Tt + 1 + t));  // seq 65+t
        epi(ys + (size_t)t * Bb * Hh);
        if (t < Tt - 1) signal((unsigned)(Tt + 2 + t));  // seq 66..128
    }
}

// ---------------- out = ys @ W_out + b_out; 64 rows/wave ----------------
__global__ __launch_bounds__(256) void k_out(const bf16* __restrict__ ys, const bf16* __restrict__ WT,
                                             const float* __restrict__ bias, float* __restrict__ out) {
    const int lane = threadIdx.x & 63, wv = threadIdx.x >> 6;
    const int m0w = blockIdx.x * 256 + wv * 64;
    const int c0 = blockIdx.y * 64;
    const int koff = (lane >> 4) * 8;
    f32x4 acc[4][4];
#pragma unroll
    for (int m = 0; m < 4; ++m)
#pragma unroll
        for (int s = 0; s < 4; ++s) acc[m][s] = f32x4{0.f, 0.f, 0.f, 0.f};

    const bf16* ap = ys + (size_t)(m0w + (lane & 15)) * Hh + koff;
#pragma unroll
    for (int kc = 0; kc < 16; ++kc) {
        bf16x8 a0 = *(const bf16x8*)(ap + kc * 32);
        bf16x8 a1 = *(const bf16x8*)(ap + 16 * Hh + kc * 32);
        bf16x8 a2 = *(const bf16x8*)(ap + 32 * Hh + kc * 32);
        bf16x8 a3 = *(const bf16x8*)(ap + 48 * Hh + kc * 32);
#pragma unroll
        for (int s = 0; s < 4; ++s) {
            bf16x8 b = *(const bf16x8*)(WT + (size_t)(c0 + s * 16 + (lane & 15)) * Hh + kc * 32 + koff);
            acc[0][s] = __builtin_amdgcn_mfma_f32_16x16x32_bf16(a0, b, acc[0][s], 0, 0, 0);
            acc[1][s] = __builtin_amdgcn_mfma_f32_16x16x32_bf16(a1, b, acc[1][s], 0, 0, 0);
            acc[2][s] = __builtin_amdgcn_mfma_f32_16x16x32_bf16(a2, b, acc[2][s], 0, 0, 0);
            acc[3][s] = __builtin_amdgcn_mfma_f32_16x16x32_bf16(a3, b, acc[3][s], 0, 0, 0);
        }
    }
#pragma unroll
    for (int m = 0; m < 4; ++m)
#pragma unroll
        for (int s = 0; s < 4; ++s) {
            int col = c0 + s * 16 + (lane & 15);
            float bv = bias[col];
#pragma unroll
            for (int r = 0; r < 4; ++r) {
                int row = m0w + m * 16 + (lane >> 4) * 4 + r;
                out[(size_t)row * Dd + col] = acc[m][s][r] + bv;
            }
        }
}

extern "C" void kernel_launch(void* const* d_in, const int* in_sizes, int n_in,
                              void* d_out, int out_size, void* d_ws, size_t ws_size,
                              hipStream_t stream) {
    const float* past = (const float*)d_in[0];
    const float* fut = (const float*)d_in[1];
    const float* noise = (const float*)d_in[2];
    const float* W_emb = (const float*)d_in[3];
    const float* b_emb = (const float*)d_in[4];
    const float* W_ih_enc = (const float*)d_in[5];
    const float* W_hh_enc = (const float*)d_in[6];
    const float* b_ih_enc = (const float*)d_in[7];
    const float* b_hh_enc = (const float*)d_in[8];
    const float* W_ih_dec = (const float*)d_in[9];
    const float* W_hh_dec = (const float*)d_in[10];
    const float* b_ih_dec = (const float*)d_in[11];
    const float* b_hh_dec = (const float*)d_in[12];
    const float* W_out = (const float*)d_in[13];
    const float* b_out = (const float*)d_in[14];
    float* out = (float*)d_out;

    char* w = (char*)d_ws;
    auto alloc = [&](size_t bytes) {
        char* p = w;
        w += (bytes + 255) & ~(size_t)255;
        return p;
    };
    bf16* embP = (bf16*)alloc((size_t)Tt * Bb * Ee * 2);
    bf16* embF = (bf16*)alloc((size_t)Tt * Bb * Ee * 2);
    bf16* ys = (bf16*)alloc((size_t)Tt * Bb * Hh * 2);
    bf16* hA = (bf16*)alloc((size_t)Bb * Hh * 2);
    bf16* hB = (bf16*)alloc((size_t)Bb * Hh * 2);
    bf16* WembT = (bf16*)alloc((size_t)Ee * Dd * 2);
    bf16* WihEncT = (bf16*)alloc((size_t)H3 * Ee * 2);
    bf16* WhhEncT = (bf16*)alloc((size_t)H3 * Hh * 2);
    bf16* WihDecT = (bf16*)alloc((size_t)H3 * Ee * 2);
    bf16* WhhDecT = (bf16*)alloc((size_t)H3 * Hh * 2);
    bf16* WoutT = (bf16*)alloc((size_t)Dd * Hh * 2);
    unsigned* flags = (unsigned*)alloc(16 * 4 * 16 * 16 * sizeof(unsigned));  // [im][rh][in], 64B stride

    // weight prep (all six transposes fused)
    k_prep<<<9600, 256, 0, stream>>>(W_emb, W_ih_enc, W_hh_enc, W_ih_dec, W_hh_dec, W_out,
                                     WembT, WihEncT, WhhEncT, WihDecT, WhhDecT, WoutT);

    // embeddings (past + future fused)
    k_embed<<<dim3(Tt * Bb / 128, Ee / 64, 2), 256, 0, stream>>>(past, fut, WembT, b_emb, embP, embF);

    // reset sequence flags
    hipMemsetAsync(flags, 0, 16 * 4 * 16 * 16 * sizeof(unsigned), stream);

    // cooperative persistent recurrent kernel: 256 blocks x 256 threads
    void* args[] = {(void*)&embP, (void*)&embF, (void*)&noise,
                    (void*)&WihEncT, (void*)&WhhEncT, (void*)&b_ih_enc, (void*)&b_hh_enc,
                    (void*)&WihDecT, (void*)&WhhDecT, (void*)&b_ih_dec, (void*)&b_hh_dec,
                    (void*)&hA, (void*)&hB, (void*)&ys, (void*)&flags};
    hipLaunchCooperativeKernel((const void*)k_gru_all, dim3(256), dim3(256), args, 0, stream);

    // output projection
    k_out<<<dim3(Tt * Bb / 256, Dd / 64), 256, 0, stream>>>(ys, WoutT, b_out, out);
}